// Round 9
// baseline (782.039 us; speedup 1.0000x reference)
//
#include <hip/hip_runtime.h>
#include <hip/hip_bf16.h>

typedef unsigned short u16;
typedef __bf16 bfv8 __attribute__((ext_vector_type(8)));
typedef float f32x4 __attribute__((ext_vector_type(4)));
typedef unsigned int u32x4 __attribute__((ext_vector_type(4)));

#define HH 512
#define BERT_D 768
#define XSTRIDE 769
#define BM 128
#define BN 256
#define BK 64

__device__ __forceinline__ float gelu_f(float x) {
  return 0.5f * x * (1.0f + erff(x * 0.70710678118654752440f));
}
__device__ __forceinline__ float us2f(u16 u) {
  union { unsigned int i; float f; } c; c.i = ((unsigned int)u) << 16; return c.f;
}
__device__ __forceinline__ u16 f2us(float f) {
  union { float f; unsigned int i; } c; c.f = f;
  unsigned int i = c.i;
  i += 0x7FFFu + ((i >> 16) & 1u);
  return (u16)(i >> 16);
}
__device__ __forceinline__ void gl_lds16(const u16* g, u16* l) {
  __builtin_amdgcn_global_load_lds((const __attribute__((address_space(1))) void*)g,
                                   (__attribute__((address_space(3))) void*)l, 16, 0, 0);
}

// ---------------- idx extraction ----------------
__global__ void k_idx(const float* __restrict__ x, int* __restrict__ idx, int Nn) {
  int i = blockIdx.x * blockDim.x + threadIdx.x;
  if (i < Nn) idx[i] = (int)x[(size_t)i * XSTRIDE + BERT_D];
}

__global__ void k_transpose_bf16(const float* __restrict__ src, u16* __restrict__ dst,
                                 int K, int Nn) {
  int i = blockIdx.x * blockDim.x + threadIdx.x;
  if (i >= K * Nn) return;
  int k = i / Nn, j = i - k * Nn;
  dst[(size_t)j * K + k] = f2us(src[i]);
}

// ---------------- graph prep ----------------
__global__ void k_deg(const int* __restrict__ dst, int* __restrict__ deg, int E) {
  int e = blockIdx.x * blockDim.x + threadIdx.x;
  if (e < E) atomicAdd(&deg[dst[e]], 1);
}

__launch_bounds__(256)
__global__ void k_part(const int* __restrict__ deg, int* __restrict__ part, int Nn) {
  const int i = blockIdx.x * 256 + threadIdx.x;
  int v = (i < Nn) ? deg[i] : 0;
#pragma unroll
  for (int o = 32; o; o >>= 1) v += __shfl_xor(v, o);
  __shared__ int ws4[4];
  if ((threadIdx.x & 63) == 0) ws4[threadIdx.x >> 6] = v;
  __syncthreads();
  if (threadIdx.x == 0) part[blockIdx.x] = ws4[0] + ws4[1] + ws4[2] + ws4[3];
}

__launch_bounds__(256)
__global__ void k_scan_part(int* __restrict__ part, int* __restrict__ row_ptr,
                            int nb, int Nn) {
  __shared__ int sm[256];
  const int t = threadIdx.x;
  int v = (t < nb) ? part[t] : 0;
  sm[t] = v;
  __syncthreads();
  for (int d = 1; d < 256; d <<= 1) {
    int u = (t >= d) ? sm[t - d] : 0;
    __syncthreads();
    sm[t] += u;
    __syncthreads();
  }
  if (t < nb) part[t] = sm[t] - v;
  if (t == 255) row_ptr[Nn] = sm[255];
}

__launch_bounds__(256)
__global__ void k_scan_write(const int* __restrict__ deg, const int* __restrict__ part,
                             int* __restrict__ row_ptr, int* __restrict__ cursor,
                             float* __restrict__ dinv, int Nn) {
  __shared__ int sm[256];
  const int t = threadIdx.x;
  const int i = blockIdx.x * 256 + t;
  int v = (i < Nn) ? deg[i] : 0;
  sm[t] = v;
  __syncthreads();
  for (int d = 1; d < 256; d <<= 1) {
    int u = (t >= d) ? sm[t - d] : 0;
    __syncthreads();
    sm[t] += u;
    __syncthreads();
  }
  if (i < Nn) {
    int pre = part[blockIdx.x] + sm[t] - v;
    row_ptr[i] = pre;
    cursor[i] = pre;
    dinv[i] = rsqrtf((float)v + 1.0f);
  }
}

__global__ void k_csr(const int* __restrict__ src, const int* __restrict__ dst,
                      int* __restrict__ cursor, int* __restrict__ csr_src, int E) {
  int e = blockIdx.x * blockDim.x + threadIdx.x;
  if (e >= E) return;
  int d = dst[e];
  int pos = atomicAdd(&cursor[d], 1);
  csr_src[pos] = src[e];
}

// ================= GEMMs: 8-wave, double-buffered LDS, 1 barrier per k-step =====
// Swizzle invariant: LDS[row][g16] = global[row][g16 ^ (row&7)]
//   DMA staging: linear LDS dest, source col granule (t&7)^((t>>3)&7)
//   reads:       granule (ks*4+kq) ^ (lr&7)

// ---------------- GEMM1: h0 = bf16(x[:, :768]) @ sem_W^T + bias + emb[idx] ----
// A reg-staged from f32 x (T14 split: load early, ds_write after MFMA); B via DMA.
__launch_bounds__(512, 2)
__global__ void k_gemm1(const float* __restrict__ xf,
                        const u16* __restrict__ B, int ldb,
                        u16* __restrict__ C, int M,
                        const float* __restrict__ bias,
                        const float* __restrict__ emb,
                        const int* __restrict__ idx) {
  __shared__ alignas(16) u16 As[2][BM * BK];
  __shared__ alignas(16) u16 Bs[2][BN * BK];
  const int t = threadIdx.x;
  const int l = t & 63;
  const int w = t >> 6;            // 0..7
  const int wro = (w >> 2) * 64;   // 2 wave-rows
  const int wco = (w & 3) * 64;    // 4 wave-cols
  const int lr = l & 15;
  const int kq = l >> 4;
  const int rsw = lr & 7;
  const int nwg = gridDim.x;
  const int id = blockIdx.x;
  const int q8 = nwg >> 3, r8 = nwg & 7;
  const int xcd = id & 7, rk = id >> 3;
  const int swz = (xcd < r8 ? xcd * (q8 + 1) : r8 * (q8 + 1) + (xcd - r8) * q8) + rk;
  const int brow = (swz >> 1) * BM;
  const int bcol = (swz & 1) * BN;

  const int ssw8 = (((t & 7) ^ ((t >> 3) & 7)) * 8);  // B staging source col (elems)
  const int arow = t >> 2;          // A: row 0..127
  const int ag0 = (t & 3) * 2;      // A: granule pair base 0,2,4,6
  const int arsw = arow & 7;

  int agr = brow + arow; if (agr > M - 1) agr = M - 1;
  const float* xrow = xf + (size_t)agr * XSTRIDE;

  float av[16];

  f32x4 acc[4][4] = {};

  auto stageB = [&](int k0, int buf) {
#pragma unroll
    for (int i = 0; i < 4; ++i) {
      const int r = i * 64 + (t >> 3);
      gl_lds16(B + (size_t)(bcol + r) * ldb + (k0 + ssw8), &Bs[buf][(i * 512 + t) * 8]);
    }
  };
  auto loadA = [&](int k0) {
#pragma unroll
    for (int j = 0; j < 2; ++j) {
      const int sg = (ag0 + j) ^ arsw;
      const float* xp = xrow + k0 + sg * 8;
#pragma unroll
      for (int e = 0; e < 8; ++e) av[j * 8 + e] = xp[e];
    }
  };
  auto writeA = [&](int buf) {
#pragma unroll
    for (int j = 0; j < 2; ++j) {
      union { u16 h[8]; uint4 q; } pk;
#pragma unroll
      for (int e = 0; e < 8; ++e) pk.h[e] = f2us(av[j * 8 + e]);
      *(uint4*)(&As[buf][arow * 64 + (ag0 + j) * 8]) = pk.q;
    }
  };

  loadA(0);
  stageB(0, 0);
  writeA(0);
  __syncthreads();

  int cur = 0;
  for (int st = 0; st < BERT_D / BK; ++st) {
    const bool hn = (st + 1 < BERT_D / BK);
    if (hn) { loadA((st + 1) * BK); stageB((st + 1) * BK, cur ^ 1); }
    const u16* Ac = As[cur];
    const u16* Bc = Bs[cur];
#pragma unroll
    for (int ks = 0; ks < 2; ++ks) {
      bfv8 af[4], bfr[4];
      const int rg = ((ks * 4 + kq) ^ rsw) * 8;
#pragma unroll
      for (int m = 0; m < 4; ++m)
        af[m] = __builtin_bit_cast(bfv8, *(const uint4*)(Ac + (wro + m * 16 + lr) * 64 + rg));
#pragma unroll
      for (int n = 0; n < 4; ++n)
        bfr[n] = __builtin_bit_cast(bfv8, *(const uint4*)(Bc + (wco + n * 16 + lr) * 64 + rg));
#pragma unroll
      for (int m = 0; m < 4; ++m)
#pragma unroll
        for (int n = 0; n < 4; ++n)
          acc[m][n] = __builtin_amdgcn_mfma_f32_16x16x32_bf16(af[m], bfr[n], acc[m][n], 0, 0, 0);
    }
    if (hn) writeA(cur ^ 1);
    __syncthreads();
    cur ^= 1;
  }

#pragma unroll
  for (int m = 0; m < 4; ++m) {
#pragma unroll
    for (int r = 0; r < 4; ++r) {
      const int row = brow + wro + m * 16 + (l >> 4) * 4 + r;
      if (row >= M) continue;
#pragma unroll
      for (int n = 0; n < 4; ++n) {
        const int col = bcol + wco + n * 16 + lr;
        float v = acc[m][n][r] + bias[col] + emb[idx[row] * HH + col];
        C[(size_t)row * HH + col] = f2us(v);
      }
    }
  }
}

// ---------------- GEMM (bf16 A): C = A @ B^T, dbuf 2-phase ----------------
// EPI=0: plain   EPI=2: row-scale by dscale[row]
template <int EPI>
__launch_bounds__(512, 2)
__global__ void k_gemm_bt(const u16* __restrict__ A, int lda,
                          const u16* __restrict__ B, int ldb,
                          u16* __restrict__ C, int M, int Kd,
                          const float* __restrict__ dscale) {
  __shared__ alignas(16) u16 As[2][BM * BK];
  __shared__ alignas(16) u16 Bs[2][BN * BK];
  const int t = threadIdx.x;
  const int l = t & 63;
  const int w = t >> 6;
  const int wro = (w >> 2) * 64;
  const int wco = (w & 3) * 64;
  const int lr = l & 15;
  const int kq = l >> 4;
  const int rsw = lr & 7;
  const int nwg = gridDim.x;
  const int id = blockIdx.x;
  const int q8 = nwg >> 3, r8 = nwg & 7;
  const int xcd = id & 7, rk = id >> 3;
  const int swz = (xcd < r8 ? xcd * (q8 + 1) : r8 * (q8 + 1) + (xcd - r8) * q8) + rk;
  const int brow = (swz >> 1) * BM;
  const int bcol = (swz & 1) * BN;

  const int ssw8 = (((t & 7) ^ ((t >> 3) & 7)) * 8);
  const int srow = t >> 3;   // 0..63

  f32x4 acc[4][4] = {};

  auto stage = [&](int k0, int buf) {
#pragma unroll
    for (int i = 0; i < 2; ++i) {
      const int r = i * 64 + srow;
      int gr = brow + r; if (gr > M - 1) gr = M - 1;
      gl_lds16(A + (size_t)gr * lda + (k0 + ssw8), &As[buf][(i * 512 + t) * 8]);
    }
#pragma unroll
    for (int i = 0; i < 4; ++i) {
      const int r = i * 64 + srow;
      gl_lds16(B + (size_t)(bcol + r) * ldb + (k0 + ssw8), &Bs[buf][(i * 512 + t) * 8]);
    }
  };

  stage(0, 0);
  __syncthreads();

  const int nst = Kd / BK;
  int cur = 0;
  for (int st = 0; st < nst; ++st) {
    if (st + 1 < nst) stage((st + 1) * BK, cur ^ 1);
    const u16* Ac = As[cur];
    const u16* Bc = Bs[cur];
#pragma unroll
    for (int ks = 0; ks < 2; ++ks) {
      bfv8 af[4], bfr[4];
      const int rg = ((ks * 4 + kq) ^ rsw) * 8;
#pragma unroll
      for (int m = 0; m < 4; ++m)
        af[m] = __builtin_bit_cast(bfv8, *(const uint4*)(Ac + (wro + m * 16 + lr) * 64 + rg));
#pragma unroll
      for (int n = 0; n < 4; ++n)
        bfr[n] = __builtin_bit_cast(bfv8, *(const uint4*)(Bc + (wco + n * 16 + lr) * 64 + rg));
#pragma unroll
      for (int m = 0; m < 4; ++m)
#pragma unroll
        for (int n = 0; n < 4; ++n)
          acc[m][n] = __builtin_amdgcn_mfma_f32_16x16x32_bf16(af[m], bfr[n], acc[m][n], 0, 0, 0);
    }
    __syncthreads();
    cur ^= 1;
  }

#pragma unroll
  for (int m = 0; m < 4; ++m) {
#pragma unroll
    for (int r = 0; r < 4; ++r) {
      const int row = brow + wro + m * 16 + (l >> 4) * 4 + r;
      if (row >= M) continue;
      const float sc = (EPI == 2) ? dscale[row] : 1.0f;
#pragma unroll
      for (int n = 0; n < 4; ++n) {
        const int col = bcol + wco + n * 16 + lr;
        float v = acc[m][n][r];
        if (EPI == 2) v *= sc;
        C[(size_t)row * HH + col] = f2us(v);
      }
    }
  }
}

// ---------------- LayerNorm + GELU (one wave per row) ----------------
__launch_bounds__(256)
__global__ void k_ln_gelu(const u16* __restrict__ h0, const float* __restrict__ gw,
                          const float* __restrict__ bw, u16* __restrict__ hout, int Nn) {
  const int wid = (int)((blockIdx.x * (long long)blockDim.x + threadIdx.x) >> 6);
  if (wid >= Nn) return;
  const int l = threadIdx.x & 63;
  uint4 q = *(const uint4*)(h0 + (size_t)wid * HH + l * 8);
  const u16* us = (const u16*)&q;
  float f[8]; float s = 0.f, s2 = 0.f;
#pragma unroll
  for (int j = 0; j < 8; ++j) { f[j] = us2f(us[j]); s += f[j]; s2 += f[j] * f[j]; }
#pragma unroll
  for (int o = 32; o; o >>= 1) { s += __shfl_xor(s, o); s2 += __shfl_xor(s2, o); }
  const float mean = s * (1.f / 512.f);
  const float var = s2 * (1.f / 512.f) - mean * mean;
  const float rs = rsqrtf(var + 1e-5f);
  union { u16 ov[8]; uint4 q; } o;
#pragma unroll
  for (int j = 0; j < 8; ++j) {
    int col = l * 8 + j;
    float y = (f[j] - mean) * rs * gw[col] + bw[col];
    o.ov[j] = f2us(gelu_f(y));
  }
  *(uint4*)(hout + (size_t)wid * HH + l * 8) = o.q;
}

// ---------------- GCN aggregate (R5 form: 4-deep MLP, self at end) ----------
__launch_bounds__(256)
__global__ void k_agg(const u16* __restrict__ hwS, const int* __restrict__ row_ptr,
                      const int* __restrict__ csr_src, const float* __restrict__ dinv,
                      const float* __restrict__ bias, u16* __restrict__ hout, int Nn) {
  const int wid = (int)((blockIdx.x * (long long)blockDim.x + threadIdx.x) >> 6);
  if (wid >= Nn) return;
  const int l = threadIdx.x & 63;
  const int cb = l * 8;
  float acc[8] = {0.f, 0.f, 0.f, 0.f, 0.f, 0.f, 0.f, 0.f};
  const int lo = row_ptr[wid], hi = row_ptr[wid + 1];
  const float dv = dinv[wid];
  int e = lo;
  for (; e + 4 <= hi; e += 4) {
    const int u0 = csr_src[e + 0];
    const int u1 = csr_src[e + 1];
    const int u2 = csr_src[e + 2];
    const int u3 = csr_src[e + 3];
    uint4 q0 = *(const uint4*)(hwS + (size_t)u0 * HH + cb);
    uint4 q1 = *(const uint4*)(hwS + (size_t)u1 * HH + cb);
    uint4 q2 = *(const uint4*)(hwS + (size_t)u2 * HH + cb);
    uint4 q3 = *(const uint4*)(hwS + (size_t)u3 * HH + cb);
    const u16* p0 = (const u16*)&q0;
    const u16* p1 = (const u16*)&q1;
    const u16* p2 = (const u16*)&q2;
    const u16* p3 = (const u16*)&q3;
#pragma unroll
    for (int j = 0; j < 8; ++j)
      acc[j] += (us2f(p0[j]) + us2f(p1[j])) + (us2f(p2[j]) + us2f(p3[j]));
  }
  for (; e < hi; ++e) {
    const int u = csr_src[e];
    uint4 q = *(const uint4*)(hwS + (size_t)u * HH + cb);
    const u16* p = (const u16*)&q;
#pragma unroll
    for (int j = 0; j < 8; ++j) acc[j] += us2f(p[j]);
  }
  {
    uint4 q = *(const uint4*)(hwS + (size_t)wid * HH + cb);
    const u16* p = (const u16*)&q;
#pragma unroll
    for (int j = 0; j < 8; ++j) acc[j] += us2f(p[j]);
  }
  union { u16 ov[8]; u32x4 q; } o;
#pragma unroll
  for (int j = 0; j < 8; ++j) {
    float v = acc[j] * dv + bias[cb + j];
    o.ov[j] = f2us(gelu_f(v));
  }
  __builtin_nontemporal_store(o.q, (u32x4*)(hout + (size_t)wid * HH + cb));
}

// ---------------- pooling: (G x RS) blocks, NT vector loads, atomic partials ----
#define POOL_RS 16
__launch_bounds__(256)
__global__ void k_pool2(const u16* __restrict__ h1, const u16* __restrict__ h2,
                        const int* __restrict__ batch, float* __restrict__ hg, int Nn) {
  const int g = blockIdx.x;
  const int chunk = blockIdx.y;
  const int t = threadIdx.x;
  const int w = t >> 6;
  const int l = t & 63;
  const int cb = l * 8;
  int lo, hi;
  { int a = 0, b = Nn; while (a < b) { int m = (a + b) >> 1; if (batch[m] < g) a = m + 1; else b = m; } lo = a; }
  { int a = 0, b = Nn; while (a < b) { int m = (a + b) >> 1; if (batch[m] < g + 1) a = m + 1; else b = m; } hi = a; }
  const int len = hi - lo;
  const int per = (len + POOL_RS - 1) / POOL_RS;
  const int rlo = lo + chunk * per;
  const int rhi = min(rlo + per, hi);
  float acc[8] = {};
  for (int r = rlo + w; r < rhi; r += 4) {
    u32x4 a = __builtin_nontemporal_load((const u32x4*)(h1 + (size_t)r * HH + cb));
    u32x4 b = __builtin_nontemporal_load((const u32x4*)(h2 + (size_t)r * HH + cb));
    const u16* ua = (const u16*)&a;
    const u16* ub = (const u16*)&b;
#pragma unroll
    for (int j = 0; j < 8; ++j) acc[j] += us2f(ua[j]) + us2f(ub[j]);
  }
  __shared__ float red[4][HH];
#pragma unroll
  for (int j = 0; j < 8; ++j) red[w][cb + j] = acc[j];
  __syncthreads();
  if (w == 0) {
#pragma unroll
    for (int j = 0; j < 8; ++j) {
      const int col = cb + j;
      float s = red[0][col] + red[1][col] + red[2][col] + red[3][col];
      if (s != 0.f) atomicAdd(&hg[(size_t)g * HH + col], s);
    }
  }
}

// ---------------- classifier (one block per group; divides by count) ---------
__launch_bounds__(256)
__global__ void k_cls(const float* __restrict__ hg, const int* __restrict__ batch,
                      const float* __restrict__ W1, const float* __restrict__ b1,
                      const float* __restrict__ W2, const float* __restrict__ b2,
                      float* __restrict__ out, int Nn) {
  const int g = blockIdx.x;
  const int t = threadIdx.x;
  __shared__ float hl[512];
  __shared__ float zl[512];
  __shared__ float pr[512];
  int lo, hi;
  { int a = 0, b = Nn; while (a < b) { int m = (a + b) >> 1; if (batch[m] < g) a = m + 1; else b = m; } lo = a; }
  { int a = 0, b = Nn; while (a < b) { int m = (a + b) >> 1; if (batch[m] < g + 1) a = m + 1; else b = m; } hi = a; }
  const float inv = 1.0f / fmaxf((float)(hi - lo), 1.0f);
  hl[t] = hg[(size_t)g * HH + t] * inv;
  hl[t + 256] = hg[(size_t)g * HH + t + 256] * inv;
  __syncthreads();
#pragma unroll
  for (int jj = 0; jj < 2; ++jj) {
    const int j = t + jj * 256;
    float a = b1[j];
    for (int k = 0; k < 512; ++k) a += hl[k] * W1[k * HH + j];
    zl[j] = gelu_f(a);
  }
  __syncthreads();
  float p0 = 0.f, p1 = 0.f;
  for (int k = t; k < 512; k += 256) { p0 += zl[k] * W2[k * 2]; p1 += zl[k] * W2[k * 2 + 1]; }
  pr[t] = p0; pr[t + 256] = p1;
  __syncthreads();
  for (int s2 = 128; s2; s2 >>= 1) {
    if (t < s2) { pr[t] += pr[t + s2]; pr[t + 256] += pr[t + 256 + s2]; }
    __syncthreads();
  }
  if (t == 0) { out[g * 2] = pr[0] + b2[0]; out[g * 2 + 1] = pr[256] + b2[1]; }
}

// ---------------- host ----------------
extern "C" void kernel_launch(void* const* d_in, const int* in_sizes, int n_in,
                              void* d_out, int out_size, void* d_ws, size_t ws_size,
                              hipStream_t stream) {
  const float* x        = (const float*)d_in[0];
  const int*   eidx     = (const int*)d_in[1];
  const int*   batch    = (const int*)d_in[2];
  const float* sem_W    = (const float*)d_in[3];
  const float* sem_b    = (const float*)d_in[4];
  const float* sl_emb   = (const float*)d_in[5];
  const float* ln_g     = (const float*)d_in[6];
  const float* ln_b     = (const float*)d_in[7];
  const float* W1       = (const float*)d_in[8];
  const float* b1       = (const float*)d_in[9];
  const float* W2       = (const float*)d_in[10];
  const float* b2       = (const float*)d_in[11];
  const float* cW1      = (const float*)d_in[12];
  const float* cb1      = (const float*)d_in[13];
  const float* cW2      = (const float*)d_in[14];
  const float* cb2      = (const float*)d_in[15];
  const int N_ = in_sizes[2];
  const int E_ = in_sizes[1] / 2;
  const int G_ = out_size / 2;
  const int* src = eidx;
  const int* dst = eidx + E_;

  char* ws = (char*)d_ws;
  size_t off = 0;
  auto alloc = [&](size_t bytes) -> void* {
    void* p = (void*)(ws + off);
    off += (bytes + 255) & ~(size_t)255;
    return p;
  };
  u16* h1 = (u16*)alloc((size_t)N_ * HH * sizeof(u16));
  u16* h0 = (u16*)alloc((size_t)N_ * HH * sizeof(u16));
  u16* hw = h0;                                       // reuse region B
  u16* h = (u16*)alloc((size_t)N_ * HH * sizeof(u16));
  u16* h2 = h;                                        // reuse region C
  u16* semW_T = (u16*)alloc((size_t)HH * BERT_D * sizeof(u16));
  u16* W1T    = (u16*)alloc((size_t)HH * HH * sizeof(u16));
  u16* W2T    = (u16*)alloc((size_t)HH * HH * sizeof(u16));
  int* idx     = (int*)alloc((size_t)N_ * 4);
  int* deg     = (int*)alloc((size_t)N_ * 4);
  float* dinv  = (float*)alloc((size_t)N_ * 4);
  int* row_ptr = (int*)alloc((size_t)(N_ + 1) * 4);
  int* cursor  = (int*)alloc((size_t)N_ * 4);
  int* csr_src = (int*)alloc((size_t)E_ * 4);
  int* part    = (int*)alloc(1024);
  float* hg    = (float*)alloc((size_t)G_ * HH * 4);

  hipMemsetAsync(deg, 0, (size_t)N_ * 4, stream);
  hipMemsetAsync(hg, 0, (size_t)G_ * HH * 4, stream);

  k_idx<<<(N_ + 255) / 256, 256, 0, stream>>>(x, idx, N_);
  k_transpose_bf16<<<(BERT_D * HH + 255) / 256, 256, 0, stream>>>(sem_W, semW_T, BERT_D, HH);
  k_transpose_bf16<<<(HH * HH + 255) / 256, 256, 0, stream>>>(W1, W1T, HH, HH);
  k_transpose_bf16<<<(HH * HH + 255) / 256, 256, 0, stream>>>(W2, W2T, HH, HH);

  const int nb = (N_ + 255) / 256;
  k_deg<<<(E_ + 255) / 256, 256, 0, stream>>>(dst, deg, E_);
  k_part<<<nb, 256, 0, stream>>>(deg, part, N_);
  k_scan_part<<<1, 256, 0, stream>>>(part, row_ptr, nb, N_);
  k_scan_write<<<nb, 256, 0, stream>>>(deg, part, row_ptr, cursor, dinv, N_);
  k_csr<<<(E_ + 255) / 256, 256, 0, stream>>>(src, dst, cursor, csr_src, E_);

  const int Mtiles = (N_ + BM - 1) / BM;
  const int wave_blocks = (N_ + 3) / 4;
  const int gemm_grid = Mtiles * (HH / BN);   // 1-D, swizzled in-kernel

  // h0 = bf16(x) @ sem_W + sem_b + slice_emb[idx]   (conversion fused)
  k_gemm1<<<gemm_grid, 512, 0, stream>>>(
      x, semW_T, BERT_D, h0, N_, sem_b, sl_emb, idx);
  // h = gelu(LN(h0))
  k_ln_gelu<<<wave_blocks, 256, 0, stream>>>(h0, ln_g, ln_b, h, N_);
  // conv1: hwS = (h @ W1) * dinv[row] ; h1 = gelu((agg+self)*dinv + b1)
  k_gemm_bt<2><<<gemm_grid, 512, 0, stream>>>(
      h, HH, W1T, HH, hw, N_, HH, dinv);
  k_agg<<<wave_blocks, 256, 0, stream>>>(hw, row_ptr, csr_src, dinv, b1, h1, N_);
  // conv2: hwS = (h1 @ W2) * dinv[row] ; h2 = gelu((agg+self)*dinv + b2)
  k_gemm_bt<2><<<gemm_grid, 512, 0, stream>>>(
      h1, HH, W2T, HH, hw, N_, HH, dinv);
  k_agg<<<wave_blocks, 256, 0, stream>>>(hw, row_ptr, csr_src, dinv, b2, h2, N_);
  // pool (h1 + h2 residual fused) + classifier
  k_pool2<<<dim3(G_, POOL_RS), 256, 0, stream>>>(h1, h2, batch, hg, N_);
  k_cls<<<G_, 256, 0, stream>>>(hg, batch, cW1, cb1, cW2, cb2, (float*)d_out, N_);
}

// Round 11
// 748.287 us; speedup vs baseline: 1.0451x; 1.0451x over previous
//
#include <hip/hip_runtime.h>
#include <hip/hip_bf16.h>

typedef unsigned short u16;
typedef __bf16 bfv8 __attribute__((ext_vector_type(8)));
typedef float f32x4 __attribute__((ext_vector_type(4)));
typedef unsigned int u32x4 __attribute__((ext_vector_type(4)));

#define HH 512
#define BERT_D 768
#define XSTRIDE 769
#define BM 64
#define BN 256
#define BK 64

#define FENCE asm volatile("" ::: "memory")
#define SBAR  do { FENCE; __builtin_amdgcn_s_barrier(); FENCE; } while (0)

__device__ __forceinline__ float gelu_f(float x) {
  return 0.5f * x * (1.0f + erff(x * 0.70710678118654752440f));
}
__device__ __forceinline__ float us2f(u16 u) {
  union { unsigned int i; float f; } c; c.i = ((unsigned int)u) << 16; return c.f;
}
__device__ __forceinline__ u16 f2us(float f) {
  union { float f; unsigned int i; } c; c.f = f;
  unsigned int i = c.i;
  i += 0x7FFFu + ((i >> 16) & 1u);
  return (u16)(i >> 16);
}
__device__ __forceinline__ void gl_lds16(const u16* g, u16* l) {
  __builtin_amdgcn_global_load_lds((const __attribute__((address_space(1))) void*)g,
                                   (__attribute__((address_space(3))) void*)l, 16, 0, 0);
}

// ---------------- idx extraction ----------------
__global__ void k_idx(const float* __restrict__ x, int* __restrict__ idx, int Nn) {
  int i = blockIdx.x * blockDim.x + threadIdx.x;
  if (i < Nn) idx[i] = (int)x[(size_t)i * XSTRIDE + BERT_D];
}

__global__ void k_transpose_bf16(const float* __restrict__ src, u16* __restrict__ dst,
                                 int K, int Nn) {
  int i = blockIdx.x * blockDim.x + threadIdx.x;
  if (i >= K * Nn) return;
  int k = i / Nn, j = i - k * Nn;
  dst[(size_t)j * K + k] = f2us(src[i]);
}

// ---------------- graph prep ----------------
__global__ void k_deg(const int* __restrict__ dst, int* __restrict__ deg, int E) {
  int e = blockIdx.x * blockDim.x + threadIdx.x;
  if (e < E) atomicAdd(&deg[dst[e]], 1);
}

__launch_bounds__(256)
__global__ void k_part(const int* __restrict__ deg, int* __restrict__ part, int Nn) {
  const int i = blockIdx.x * 256 + threadIdx.x;
  int v = (i < Nn) ? deg[i] : 0;
#pragma unroll
  for (int o = 32; o; o >>= 1) v += __shfl_xor(v, o);
  __shared__ int ws4[4];
  if ((threadIdx.x & 63) == 0) ws4[threadIdx.x >> 6] = v;
  __syncthreads();
  if (threadIdx.x == 0) part[blockIdx.x] = ws4[0] + ws4[1] + ws4[2] + ws4[3];
}

__launch_bounds__(256)
__global__ void k_scan_part(int* __restrict__ part, int* __restrict__ row_ptr,
                            int nb, int Nn) {
  __shared__ int sm[256];
  const int t = threadIdx.x;
  int v = (t < nb) ? part[t] : 0;
  sm[t] = v;
  __syncthreads();
  for (int d = 1; d < 256; d <<= 1) {
    int u = (t >= d) ? sm[t - d] : 0;
    __syncthreads();
    sm[t] += u;
    __syncthreads();
  }
  if (t < nb) part[t] = sm[t] - v;
  if (t == 255) row_ptr[Nn] = sm[255];
}

__launch_bounds__(256)
__global__ void k_scan_write(const int* __restrict__ deg, const int* __restrict__ part,
                             int* __restrict__ row_ptr, int* __restrict__ cursor,
                             float* __restrict__ dinv, int Nn) {
  __shared__ int sm[256];
  const int t = threadIdx.x;
  const int i = blockIdx.x * 256 + t;
  int v = (i < Nn) ? deg[i] : 0;
  sm[t] = v;
  __syncthreads();
  for (int d = 1; d < 256; d <<= 1) {
    int u = (t >= d) ? sm[t - d] : 0;
    __syncthreads();
    sm[t] += u;
    __syncthreads();
  }
  if (i < Nn) {
    int pre = part[blockIdx.x] + sm[t] - v;
    row_ptr[i] = pre;
    cursor[i] = pre;
    dinv[i] = rsqrtf((float)v + 1.0f);
  }
}

__global__ void k_csr(const int* __restrict__ src, const int* __restrict__ dst,
                      int* __restrict__ cursor, int* __restrict__ csr_src, int E) {
  int e = blockIdx.x * blockDim.x + threadIdx.x;
  if (e >= E) return;
  int d = dst[e];
  int pos = atomicAdd(&cursor[d], 1);
  csr_src[pos] = src[e];
}

// ============ GEMMs: 64x256 tile, dbuf LDS (80KB, 2 blk/CU), counted vmcnt ======
// Swizzle invariant: LDS[row][g16] = global[row][g16 ^ (row&7)]
//   staging: per-lane-linear LDS dest, source granule (t&7)^((t>>3)&7)
//   reads:   granule (ks*4+kq) ^ (lr&7)
// Robust counting rule: the wait before compute is vmcnt(#DMAs of the NEWEST
// tile), and that tile's DMAs are issued last — stray/extra VMEM only makes
// the wait stricter, never unsafe.

// ---------------- GEMM (bf16 A): C = A @ B^T ----------------
// EPI=0: plain   EPI=2: row-scale by dscale[row]
template <int EPI>
__launch_bounds__(256, 2)
__global__ void k_gemm_bt(const u16* __restrict__ A, int lda,
                          const u16* __restrict__ B, int ldb,
                          u16* __restrict__ C, int M, int Kd,
                          const float* __restrict__ dscale) {
  __shared__ alignas(16) u16 As[2][BM * BK];
  __shared__ alignas(16) u16 Bs[2][BN * BK];
  const int t = threadIdx.x;
  const int l = t & 63;
  const int w = t >> 6;
  const int wco = w * 64;
  const int lr = l & 15;
  const int kq = l >> 4;
  const int rsw = lr & 7;
  const int nwg = gridDim.x;
  const int id = blockIdx.x;
  const int q8 = nwg >> 3, r8 = nwg & 7;
  const int xcd = id & 7, rk = id >> 3;
  const int swz = (xcd < r8 ? xcd * (q8 + 1) : r8 * (q8 + 1) + (xcd - r8) * q8) + rk;
  const int brow = (swz >> 1) * BM;
  const int bcol = (swz & 1) * BN;

  const int ssw8 = (((t & 7) ^ ((t >> 3) & 7)) * 8);
  const int sr = t >> 3;   // staging row within 32-row group

  f32x4 acc[4][4] = {};

  // 10 VMEM per call (2 A + 8 B)
  auto stage = [&](int k0, int buf) {
#pragma unroll
    for (int i = 0; i < 2; ++i) {               // A: 64 x 64
      int gr = brow + i * 32 + sr; if (gr > M - 1) gr = M - 1;
      gl_lds16(A + (size_t)gr * lda + (k0 + ssw8), &As[buf][(i * 256 + t) * 8]);
    }
#pragma unroll
    for (int i = 0; i < 8; ++i) {               // B: 256 x 64  (8 x 32 rows)
      const int r = i * 32 + sr;
      gl_lds16(B + (size_t)(bcol + r) * ldb + (k0 + ssw8), &Bs[buf][(i * 256 + t) * 8]);
    }
  };

  auto compute = [&](int buf) {
#pragma unroll
    for (int ks = 0; ks < 2; ++ks) {
      bfv8 af[4], bfr[4];
      const int rg = ((ks * 4 + kq) ^ rsw) * 8;
#pragma unroll
      for (int m = 0; m < 4; ++m)
        af[m] = __builtin_bit_cast(bfv8, *(const uint4*)(&As[buf][(m * 16 + lr) * 64 + rg]));
#pragma unroll
      for (int n = 0; n < 4; ++n)
        bfr[n] = __builtin_bit_cast(bfv8, *(const uint4*)(&Bs[buf][(wco + n * 16 + lr) * 64 + rg]));
#pragma unroll
      for (int m = 0; m < 4; ++m)
#pragma unroll
        for (int n = 0; n < 4; ++n)
          acc[m][n] = __builtin_amdgcn_mfma_f32_16x16x32_bf16(af[m], bfr[n], acc[m][n], 0, 0, 0);
    }
  };

  stage(0, 0);                        // 10 in flight
  const int nst = Kd / BK;
  int cur = 0;
  for (int st = 0; st < nst; ++st) {
    if (st + 1 < nst) {
      stage((st + 1) * BK, cur ^ 1);  // +10 (newest)
      asm volatile("s_waitcnt vmcnt(10)" ::: "memory");   // drain tile st
    } else {
      asm volatile("s_waitcnt vmcnt(0)" ::: "memory");
    }
    SBAR;
    compute(cur);
    asm volatile("s_waitcnt lgkmcnt(0)" ::: "memory");
    SBAR;
    cur ^= 1;
  }

#pragma unroll
  for (int m = 0; m < 4; ++m) {
#pragma unroll
    for (int r = 0; r < 4; ++r) {
      const int row = brow + m * 16 + (l >> 4) * 4 + r;
      if (row >= M) continue;
      const float sc = (EPI == 2) ? dscale[row] : 1.0f;
#pragma unroll
      for (int n = 0; n < 4; ++n) {
        const int col = bcol + wco + n * 16 + lr;
        float v = acc[m][n][r];
        if (EPI == 2) v *= sc;
        C[(size_t)row * HH + col] = f2us(v);
      }
    }
  }
}

// ---------------- GEMM1: h0 = bf16(x[:, :768]) @ sem_W^T + bias + emb[idx] ----
// A reg-staged from f32 x (scalar loads; compiler-drained at packA); B via DMA.
__launch_bounds__(256, 2)
__global__ void k_gemm1(const float* __restrict__ xf,
                        const u16* __restrict__ B, int ldb,
                        u16* __restrict__ C, int M,
                        const float* __restrict__ bias,
                        const float* __restrict__ emb,
                        const int* __restrict__ idx) {
  __shared__ alignas(16) u16 As[2][BM * BK];
  __shared__ alignas(16) u16 Bs[2][BN * BK];
  const int t = threadIdx.x;
  const int l = t & 63;
  const int w = t >> 6;
  const int wco = w * 64;
  const int lr = l & 15;
  const int kq = l >> 4;
  const int rsw = lr & 7;
  const int nwg = gridDim.x;
  const int id = blockIdx.x;
  const int q8 = nwg >> 3, r8 = nwg & 7;
  const int xcd = id & 7, rk = id >> 3;
  const int swz = (xcd < r8 ? xcd * (q8 + 1) : r8 * (q8 + 1) + (xcd - r8) * q8) + rk;
  const int brow = (swz >> 1) * BM;
  const int bcol = (swz & 1) * BN;

  const int ssw8 = (((t & 7) ^ ((t >> 3) & 7)) * 8);
  const int sr = t >> 3;

  // A staging rows (clamped); source cols pre-swizzled, LDS dest per-lane-linear
  int ar0 = brow + sr;        if (ar0 > M - 1) ar0 = M - 1;
  int ar1 = brow + 32 + sr;   if (ar1 > M - 1) ar1 = M - 1;
  const float* xr0 = xf + (size_t)ar0 * XSTRIDE + ssw8;
  const float* xr1 = xf + (size_t)ar1 * XSTRIDE + ssw8;

  float av[2][8];

  auto loadA = [&](int k0) {
#pragma unroll
    for (int e = 0; e < 8; ++e) av[0][e] = xr0[k0 + e];
#pragma unroll
    for (int e = 0; e < 8; ++e) av[1][e] = xr1[k0 + e];
  };
  auto stageB = [&](int k0, int buf) {   // 8 VMEM per call
#pragma unroll
    for (int i = 0; i < 8; ++i) {
      const int r = i * 32 + sr;
      gl_lds16(B + (size_t)(bcol + r) * ldb + (k0 + ssw8), &Bs[buf][(i * 256 + t) * 8]);
    }
  };
  auto packA = [&](int buf) {            // compiler inserts vm-wait for av here
#pragma unroll
    for (int i = 0; i < 2; ++i) {
      union { u16 h[8]; uint4 q; } pk;
#pragma unroll
      for (int e = 0; e < 8; ++e) pk.h[e] = f2us(av[i][e]);
      *(uint4*)(&As[buf][(i * 256 + t) * 8]) = pk.q;
    }
  };

  auto compute = [&](int buf, f32x4 (&acc)[4][4]) {
#pragma unroll
    for (int ks = 0; ks < 2; ++ks) {
      bfv8 af[4], bfr[4];
      const int rg = ((ks * 4 + kq) ^ rsw) * 8;
#pragma unroll
      for (int m = 0; m < 4; ++m)
        af[m] = __builtin_bit_cast(bfv8, *(const uint4*)(&As[buf][(m * 16 + lr) * 64 + rg]));
#pragma unroll
      for (int n = 0; n < 4; ++n)
        bfr[n] = __builtin_bit_cast(bfv8, *(const uint4*)(&Bs[buf][(wco + n * 16 + lr) * 64 + rg]));
#pragma unroll
      for (int m = 0; m < 4; ++m)
#pragma unroll
        for (int n = 0; n < 4; ++n)
          acc[m][n] = __builtin_amdgcn_mfma_f32_16x16x32_bf16(af[m], bfr[n], acc[m][n], 0, 0, 0);
    }
  };

  f32x4 acc[4][4] = {};

  // prologue: A0 loads first (so packA's compiler wait leaves B0 in flight)
  loadA(0);
  FENCE;
  stageB(0, 0);          // 8 DMA (newest)
  packA(0);              // compiler drains A0 only (oldest)
  asm volatile("s_waitcnt lgkmcnt(0)" ::: "memory");

  const int nst = BERT_D / BK;   // 12
  int cur = 0;
  for (int st = 0; st < nst; ++st) {
    const bool hn = (st + 1 < nst);
    if (hn) {
      stageB((st + 1) * BK, cur ^ 1);   // 8 DMA (newest before A loads)
      FENCE;
      loadA((st + 1) * BK);             // A loads stay in flight across compute
      asm volatile("s_waitcnt vmcnt(8)" ::: "memory");   // drains B_st (oldest)
    } else {
      asm volatile("s_waitcnt vmcnt(0)" ::: "memory");
    }
    SBAR;
    compute(cur, acc);
    if (hn) {
      packA(cur ^ 1);    // compiler waits for A_{st+1} here
      asm volatile("s_waitcnt lgkmcnt(0)" ::: "memory");
    } else {
      asm volatile("s_waitcnt lgkmcnt(0)" ::: "memory");
    }
    SBAR;
    cur ^= 1;
  }

#pragma unroll
  for (int m = 0; m < 4; ++m) {
#pragma unroll
    for (int r = 0; r < 4; ++r) {
      const int row = brow + m * 16 + (l >> 4) * 4 + r;
      if (row >= M) continue;
#pragma unroll
      for (int n = 0; n < 4; ++n) {
        const int col = bcol + wco + n * 16 + lr;
        float v = acc[m][n][r] + bias[col] + emb[idx[row] * HH + col];
        C[(size_t)row * HH + col] = f2us(v);
      }
    }
  }
}

// ---------------- LayerNorm + GELU (one wave per row) ----------------
__launch_bounds__(256)
__global__ void k_ln_gelu(const u16* __restrict__ h0, const float* __restrict__ gw,
                          const float* __restrict__ bw, u16* __restrict__ hout, int Nn) {
  const int wid = (int)((blockIdx.x * (long long)blockDim.x + threadIdx.x) >> 6);
  if (wid >= Nn) return;
  const int l = threadIdx.x & 63;
  uint4 q = *(const uint4*)(h0 + (size_t)wid * HH + l * 8);
  const u16* us = (const u16*)&q;
  float f[8]; float s = 0.f, s2 = 0.f;
#pragma unroll
  for (int j = 0; j < 8; ++j) { f[j] = us2f(us[j]); s += f[j]; s2 += f[j] * f[j]; }
#pragma unroll
  for (int o = 32; o; o >>= 1) { s += __shfl_xor(s, o); s2 += __shfl_xor(s2, o); }
  const float mean = s * (1.f / 512.f);
  const float var = s2 * (1.f / 512.f) - mean * mean;
  const float rs = rsqrtf(var + 1e-5f);
  union { u16 ov[8]; uint4 q; } o;
#pragma unroll
  for (int j = 0; j < 8; ++j) {
    int col = l * 8 + j;
    float y = (f[j] - mean) * rs * gw[col] + bw[col];
    o.ov[j] = f2us(gelu_f(y));
  }
  *(uint4*)(hout + (size_t)wid * HH + l * 8) = o.q;
}

// ---------------- GCN aggregate (4-deep MLP, self at end) ----------
__launch_bounds__(256)
__global__ void k_agg(const u16* __restrict__ hwS, const int* __restrict__ row_ptr,
                      const int* __restrict__ csr_src, const float* __restrict__ dinv,
                      const float* __restrict__ bias, u16* __restrict__ hout, int Nn) {
  const int wid = (int)((blockIdx.x * (long long)blockDim.x + threadIdx.x) >> 6);
  if (wid >= Nn) return;
  const int l = threadIdx.x & 63;
  const int cb = l * 8;
  float acc[8] = {0.f, 0.f, 0.f, 0.f, 0.f, 0.f, 0.f, 0.f};
  const int lo = row_ptr[wid], hi = row_ptr[wid + 1];
  const float dv = dinv[wid];
  int e = lo;
  for (; e + 4 <= hi; e += 4) {
    const int u0 = csr_src[e + 0];
    const int u1 = csr_src[e + 1];
    const int u2 = csr_src[e + 2];
    const int u3 = csr_src[e + 3];
    uint4 q0 = *(const uint4*)(hwS + (size_t)u0 * HH + cb);
    uint4 q1 = *(const uint4*)(hwS + (size_t)u1 * HH + cb);
    uint4 q2 = *(const uint4*)(hwS + (size_t)u2 * HH + cb);
    uint4 q3 = *(const uint4*)(hwS + (size_t)u3 * HH + cb);
    const u16* p0 = (const u16*)&q0;
    const u16* p1 = (const u16*)&q1;
    const u16* p2 = (const u16*)&q2;
    const u16* p3 = (const u16*)&q3;
#pragma unroll
    for (int j = 0; j < 8; ++j)
      acc[j] += (us2f(p0[j]) + us2f(p1[j])) + (us2f(p2[j]) + us2f(p3[j]));
  }
  for (; e < hi; ++e) {
    const int u = csr_src[e];
    uint4 q = *(const uint4*)(hwS + (size_t)u * HH + cb);
    const u16* p = (const u16*)&q;
#pragma unroll
    for (int j = 0; j < 8; ++j) acc[j] += us2f(p[j]);
  }
  {
    uint4 q = *(const uint4*)(hwS + (size_t)wid * HH + cb);
    const u16* p = (const u16*)&q;
#pragma unroll
    for (int j = 0; j < 8; ++j) acc[j] += us2f(p[j]);
  }
  union { u16 ov[8]; u32x4 q; } o;
#pragma unroll
  for (int j = 0; j < 8; ++j) {
    float v = acc[j] * dv + bias[cb + j];
    o.ov[j] = f2us(gelu_f(v));
  }
  __builtin_nontemporal_store(o.q, (u32x4*)(hout + (size_t)wid * HH + cb));
}

// ---------------- pooling: (G x RS) blocks, NT vector loads, atomic partials ----
#define POOL_RS 16
__launch_bounds__(256)
__global__ void k_pool2(const u16* __restrict__ h1, const u16* __restrict__ h2,
                        const int* __restrict__ batch, float* __restrict__ hg, int Nn) {
  const int g = blockIdx.x;
  const int chunk = blockIdx.y;
  const int t = threadIdx.x;
  const int w = t >> 6;
  const int l = t & 63;
  const int cb = l * 8;
  int lo, hi;
  { int a = 0, b = Nn; while (a < b) { int m = (a + b) >> 1; if (batch[m] < g) a = m + 1; else b = m; } lo = a; }
  { int a = 0, b = Nn; while (a < b) { int m = (a + b) >> 1; if (batch[m] < g + 1) a = m + 1; else b = m; } hi = a; }
  const int len = hi - lo;
  const int per = (len + POOL_RS - 1) / POOL_RS;
  const int rlo = lo + chunk * per;
  const int rhi = min(rlo + per, hi);
  float acc[8] = {};
  for (int r = rlo + w; r < rhi; r += 4) {
    u32x4 a = __builtin_nontemporal_load((const u32x4*)(h1 + (size_t)r * HH + cb));
    u32x4 b = __builtin_nontemporal_load((const u32x4*)(h2 + (size_t)r * HH + cb));
    const u16* ua = (const u16*)&a;
    const u16* ub = (const u16*)&b;
#pragma unroll
    for (int j = 0; j < 8; ++j) acc[j] += us2f(ua[j]) + us2f(ub[j]);
  }
  __shared__ float red[4][HH];
#pragma unroll
  for (int j = 0; j < 8; ++j) red[w][cb + j] = acc[j];
  __syncthreads();
  if (w == 0) {
#pragma unroll
    for (int j = 0; j < 8; ++j) {
      const int col = cb + j;
      float s = red[0][col] + red[1][col] + red[2][col] + red[3][col];
      if (s != 0.f) atomicAdd(&hg[(size_t)g * HH + col], s);
    }
  }
}

// ---------------- classifier (one block per group; divides by count) ---------
__launch_bounds__(256)
__global__ void k_cls(const float* __restrict__ hg, const int* __restrict__ batch,
                      const float* __restrict__ W1, const float* __restrict__ b1,
                      const float* __restrict__ W2, const float* __restrict__ b2,
                      float* __restrict__ out, int Nn) {
  const int g = blockIdx.x;
  const int t = threadIdx.x;
  __shared__ float hl[512];
  __shared__ float zl[512];
  __shared__ float pr[512];
  int lo, hi;
  { int a = 0, b = Nn; while (a < b) { int m = (a + b) >> 1; if (batch[m] < g) a = m + 1; else b = m; } lo = a; }
  { int a = 0, b = Nn; while (a < b) { int m = (a + b) >> 1; if (batch[m] < g + 1) a = m + 1; else b = m; } hi = a; }
  const float inv = 1.0f / fmaxf((float)(hi - lo), 1.0f);
  hl[t] = hg[(size_t)g * HH + t] * inv;
  hl[t + 256] = hg[(size_t)g * HH + t + 256] * inv;
  __syncthreads();
#pragma unroll
  for (int jj = 0; jj < 2; ++jj) {
    const int j = t + jj * 256;
    float a = b1[j];
    for (int k = 0; k < 512; ++k) a += hl[k] * W1[k * HH + j];
    zl[j] = gelu_f(a);
  }
  __syncthreads();
  float p0 = 0.f, p1 = 0.f;
  for (int k = t; k < 512; k += 256) { p0 += zl[k] * W2[k * 2]; p1 += zl[k] * W2[k * 2 + 1]; }
  pr[t] = p0; pr[t + 256] = p1;
  __syncthreads();
  for (int s2 = 128; s2; s2 >>= 1) {
    if (t < s2) { pr[t] += pr[t + s2]; pr[t + 256] += pr[t + 256 + s2]; }
    __syncthreads();
  }
  if (t == 0) { out[g * 2] = pr[0] + b2[0]; out[g * 2 + 1] = pr[256] + b2[1]; }
}

// ---------------- host ----------------
extern "C" void kernel_launch(void* const* d_in, const int* in_sizes, int n_in,
                              void* d_out, int out_size, void* d_ws, size_t ws_size,
                              hipStream_t stream) {
  const float* x        = (const float*)d_in[0];
  const int*   eidx     = (const int*)d_in[1];
  const int*   batch    = (const int*)d_in[2];
  const float* sem_W    = (const float*)d_in[3];
  const float* sem_b    = (const float*)d_in[4];
  const float* sl_emb   = (const float*)d_in[5];
  const float* ln_g     = (const float*)d_in[6];
  const float* ln_b     = (const float*)d_in[7];
  const float* W1       = (const float*)d_in[8];
  const float* b1       = (const float*)d_in[9];
  const float* W2       = (const float*)d_in[10];
  const float* b2       = (const float*)d_in[11];
  const float* cW1      = (const float*)d_in[12];
  const float* cb1      = (const float*)d_in[13];
  const float* cW2      = (const float*)d_in[14];
  const float* cb2      = (const float*)d_in[15];
  const int N_ = in_sizes[2];
  const int E_ = in_sizes[1] / 2;
  const int G_ = out_size / 2;
  const int* src = eidx;
  const int* dst = eidx + E_;

  char* ws = (char*)d_ws;
  size_t off = 0;
  auto alloc = [&](size_t bytes) -> void* {
    void* p = (void*)(ws + off);
    off += (bytes + 255) & ~(size_t)255;
    return p;
  };
  u16* h1 = (u16*)alloc((size_t)N_ * HH * sizeof(u16));
  u16* h0 = (u16*)alloc((size_t)N_ * HH * sizeof(u16));
  u16* hw = h0;                                       // reuse region B
  u16* h = (u16*)alloc((size_t)N_ * HH * sizeof(u16));
  u16* h2 = h;                                        // reuse region C
  u16* semW_T = (u16*)alloc((size_t)HH * BERT_D * sizeof(u16));
  u16* W1T    = (u16*)alloc((size_t)HH * HH * sizeof(u16));
  u16* W2T    = (u16*)alloc((size_t)HH * HH * sizeof(u16));
  int* idx     = (int*)alloc((size_t)N_ * 4);
  int* deg     = (int*)alloc((size_t)N_ * 4);
  float* dinv  = (float*)alloc((size_t)N_ * 4);
  int* row_ptr = (int*)alloc((size_t)(N_ + 1) * 4);
  int* cursor  = (int*)alloc((size_t)N_ * 4);
  int* csr_src = (int*)alloc((size_t)E_ * 4);
  int* part    = (int*)alloc(1024);
  float* hg    = (float*)alloc((size_t)G_ * HH * 4);

  hipMemsetAsync(deg, 0, (size_t)N_ * 4, stream);
  hipMemsetAsync(hg, 0, (size_t)G_ * HH * 4, stream);

  k_idx<<<(N_ + 255) / 256, 256, 0, stream>>>(x, idx, N_);
  k_transpose_bf16<<<(BERT_D * HH + 255) / 256, 256, 0, stream>>>(sem_W, semW_T, BERT_D, HH);
  k_transpose_bf16<<<(HH * HH + 255) / 256, 256, 0, stream>>>(W1, W1T, HH, HH);
  k_transpose_bf16<<<(HH * HH + 255) / 256, 256, 0, stream>>>(W2, W2T, HH, HH);

  const int nb = (N_ + 255) / 256;
  k_deg<<<(E_ + 255) / 256, 256, 0, stream>>>(dst, deg, E_);
  k_part<<<nb, 256, 0, stream>>>(deg, part, N_);
  k_scan_part<<<1, 256, 0, stream>>>(part, row_ptr, nb, N_);
  k_scan_write<<<nb, 256, 0, stream>>>(deg, part, row_ptr, cursor, dinv, N_);
  k_csr<<<(E_ + 255) / 256, 256, 0, stream>>>(src, dst, cursor, csr_src, E_);

  const int Mtiles = (N_ + BM - 1) / BM;
  const int wave_blocks = (N_ + 3) / 4;
  const int gemm_grid = Mtiles * (HH / BN);   // 1-D, swizzled in-kernel

  // h0 = bf16(x) @ sem_W + sem_b + slice_emb[idx]   (conversion fused)
  k_gemm1<<<gemm_grid, 256, 0, stream>>>(
      x, semW_T, BERT_D, h0, N_, sem_b, sl_emb, idx);
  // h = gelu(LN(h0))
  k_ln_gelu<<<wave_blocks, 256, 0, stream>>>(h0, ln_g, ln_b, h, N_);
  // conv1: hwS = (h @ W1) * dinv[row] ; h1 = gelu((agg+self)*dinv + b1)
  k_gemm_bt<2><<<gemm_grid, 256, 0, stream>>>(
      h, HH, W1T, HH, hw, N_, HH, dinv);
  k_agg<<<wave_blocks, 256, 0, stream>>>(hw, row_ptr, csr_src, dinv, b1, h1, N_);
  // conv2: hwS = (h1 @ W2) * dinv[row] ; h2 = gelu((agg+self)*dinv + b2)
  k_gemm_bt<2><<<gemm_grid, 256, 0, stream>>>(
      h1, HH, W2T, HH, hw, N_, HH, dinv);
  k_agg<<<wave_blocks, 256, 0, stream>>>(hw, row_ptr, csr_src, dinv, b2, h2, N_);
  // pool (h1 + h2 residual fused) + classifier
  k_pool2<<<dim3(G_, POOL_RS), 256, 0, stream>>>(h1, h2, batch, hg, N_);
  k_cls<<<G_, 256, 0, stream>>>(hg, batch, cW1, cb1, cW2, cb2, (float*)d_out, N_);
}